// Round 7
// baseline (960.952 us; speedup 1.0000x reference)
//
#include <hip/hip_runtime.h>
#include <stdint.h>

#define NSUP 65536
#define NQRY 65536
#define FEAT 1024
#define EMB  512
#define WAYS 256

typedef unsigned short u16;
typedef unsigned int   u32;
typedef __attribute__((ext_vector_type(8))) __bf16 bf16x8;
typedef __attribute__((ext_vector_type(4))) float  f32x4;

// RNE float -> bf16 bits
static __device__ __forceinline__ u16 f2bf(float f) {
    u32 u = __builtin_bit_cast(u32, f);
    u32 r = u + 0x7fffu + ((u >> 16) & 1u);
    return (u16)(r >> 16);
}

// async global -> LDS, 16B per lane (dest must be wave-uniform base + lane*16)
static __device__ __forceinline__ void gl_lds16(const void* g, void* l) {
    __builtin_amdgcn_global_load_lds((const __attribute__((address_space(1))) u32*)g,
                                     (__attribute__((address_space(3))) u32*)l,
                                     16, 0, 0);
}

// swizzled u16-index in a [rows][32 u16] tile: source slot s of row r stored at
// slot s ^ ((r>>1)&3); b128 fragment reads hit every bank exactly 8x (= minimum
// for wave64 b128) -> 0 conflicts (verified R4/R5: SQ_LDS_BANK_CONFLICT = 0).
static __device__ __forceinline__ int swz16(int r, int s) {
    return r * 32 + ((s ^ ((r >> 1) & 3)) * 8);
}

// ---------------- K0: W [FEAT][EMB] f32 -> Wt [EMB][FEAT] bf16 (+ zero icounts) ----------------
__global__ __launch_bounds__(256) void k0_transpose(const float* __restrict__ W,
                                                    u16* __restrict__ Wt,
                                                    int* __restrict__ icounts) {
    const int t = threadIdx.x;
    if (blockIdx.x == 0) icounts[t] = 0;   // replaces hipMemsetAsync node (~150us each)
    __shared__ float tile[64][65];
    const int bx = blockIdx.x;
    const int k0 = (bx & 15) * 64;
    const int e0 = (bx >> 4) * 64;
#pragma unroll
    for (int i = 0; i < 16; ++i) {
        int idx = t + i * 256;
        int kk = idx >> 6, ee = idx & 63;
        tile[kk][ee] = W[(size_t)(k0 + kk) * EMB + e0 + ee];
    }
    __syncthreads();
#pragma unroll
    for (int i = 0; i < 16; ++i) {
        int idx = t + i * 256;
        int ee = idx >> 6, kk = idx & 63;
        Wt[(size_t)(e0 + ee) * FEAT + k0 + kk] = f2bf(tile[kk][ee]);
    }
}

// ---------------- K1a: argmax of one-hot rows -> labels, int histogram ----------------
__global__ __launch_bounds__(256) void k1a_labels(const int* __restrict__ sl,
                                                  int* __restrict__ labels,
                                                  int* __restrict__ icounts) {
    const int row = blockIdx.x * 4 + (threadIdx.x >> 6);
    const int lane = threadIdx.x & 63;
    const int4* p = (const int4*)(sl + (size_t)row * WAYS);
    int4 v = p[lane];
    int my = -1;
    if (v.x) my = lane * 4 + 0;
    if (v.y) my = lane * 4 + 1;
    if (v.z) my = lane * 4 + 2;
    if (v.w) my = lane * 4 + 3;
#pragma unroll
    for (int m = 32; m; m >>= 1) my = max(my, __shfl_xor(my, m));
    if (lane == 0) {
        labels[row] = my;
        atomicAdd(&icounts[my], 1);
    }
}

// ---------------- K1p: exclusive prefix sum over 256 class counts ----------------
__global__ __launch_bounds__(256) void k1p_prefix(const int* __restrict__ icounts,
                                                  int* __restrict__ offs,
                                                  int* __restrict__ cursor,
                                                  float* __restrict__ countsF) {
    __shared__ int s[256];
    const int t = threadIdx.x;
    const int v = icounts[t];
    s[t] = v;
    __syncthreads();
    for (int d = 1; d < 256; d <<= 1) {
        int x = (t >= d) ? s[t - d] : 0;
        __syncthreads();
        s[t] += x;
        __syncthreads();
    }
    const int exc = s[t] - v;
    offs[t] = exc;
    cursor[t] = exc;
    countsF[t] = (float)v;
}

// ---------------- K1s: scatter row indices by class -> perm ----------------
__global__ __launch_bounds__(256) void k1s_scatter(const int* __restrict__ labels,
                                                   int* __restrict__ cursor,
                                                   int* __restrict__ perm) {
    const int r = blockIdx.x * 256 + threadIdx.x;
    const int lb = labels[r];
    const int pos = atomicAdd(&cursor[lb], 1);
    perm[pos] = r;
}

// ---------------- K1c: per-class feature sums, gather-streaming, NO atomics ----------------
__global__ __launch_bounds__(256) void k1c_classsum(const float* __restrict__ img,
                                                    const int* __restrict__ perm,
                                                    const int* __restrict__ offs,
                                                    const int* __restrict__ icounts,
                                                    float* __restrict__ sums) {
    const int c  = blockIdx.x >> 2;
    const int fs = blockIdx.x & 3;
    const int t  = threadIdx.x;
    const int base = offs[c];
    const int n    = icounts[c];
    const size_t fcol = (size_t)fs * 256 + t;
    float acc = 0.f;
    int i = 0;
    for (; i + 8 <= n; i += 8) {
        int rr[8];
#pragma unroll
        for (int u = 0; u < 8; ++u) rr[u] = perm[base + i + u];
        float v[8];
#pragma unroll
        for (int u = 0; u < 8; ++u) v[u] = img[(size_t)rr[u] * FEAT + fcol];
#pragma unroll
        for (int u = 0; u < 8; ++u) acc += v[u];
    }
    for (; i < n; ++i) acc += img[(size_t)perm[base + i] * FEAT + fcol];
    sums[(size_t)c * FEAT + fcol] = acc;
}

// ---------------- K2: protos: (sums/count) @ W  -> zp_bf16 [WAYS][EMB], p2 ----------------
// NOTE: bias b deliberately omitted everywhere — it cancels in euclidean distance.
__global__ __launch_bounds__(512) void k2_proto(const float* __restrict__ sums,
                                                const float* __restrict__ counts,
                                                const float* __restrict__ W,
                                                u16* __restrict__ zpb,
                                                float* __restrict__ p2) {
    __shared__ float proto[FEAT];
    __shared__ float red[8];
    const int c = blockIdx.x, t = threadIdx.x;
    const float inv = 1.0f / counts[c];
    proto[t]       = sums[(size_t)c * FEAT + t] * inv;
    proto[t + 512] = sums[(size_t)c * FEAT + t + 512] * inv;
    __syncthreads();
    float a0 = 0.f, a1 = 0.f, a2 = 0.f, a3 = 0.f;
#pragma unroll 8
    for (int k = 0; k < FEAT; k += 4) {
        a0 += proto[k + 0] * W[(size_t)(k + 0) * EMB + t];
        a1 += proto[k + 1] * W[(size_t)(k + 1) * EMB + t];
        a2 += proto[k + 2] * W[(size_t)(k + 2) * EMB + t];
        a3 += proto[k + 3] * W[(size_t)(k + 3) * EMB + t];
    }
    float z = (a0 + a1) + (a2 + a3);
    zpb[(size_t)c * EMB + t] = f2bf(z);
    float sq = z * z;
#pragma unroll
    for (int m = 1; m < 64; m <<= 1) sq += __shfl_xor(sq, m);
    if ((t & 63) == 0) red[t >> 6] = sq;
    __syncthreads();
    if (t == 0) {
        float s = 0.f;
#pragma unroll
        for (int i = 0; i < 8; ++i) s += red[i];
        p2[c] = s;
    }
}

// ---------------- K3: z_query GEMM: Q[65536][1024]f32 x Wt[512][1024]bf16 ----------------
// Full-N tile 128M x 512N (Q fetched ONCE), BK=32, 8 waves (2m x 4n), wave 64x128,
// 2-phase dbuf, swizzled LDS (0 conflicts), LDS exactly 80 KiB -> 2 blocks/CU.
// q2 partials per wave-column -> global q2p[4][NQRY] plain stores (no LDS, no atomics).
__global__ __launch_bounds__(512, 4) void k3_zq(const float* __restrict__ Q,
                                                const u16* __restrict__ Wt,
                                                u16* __restrict__ zq,
                                                float* __restrict__ q2p) {
    __shared__ u16 Asl[2][128 * 32];   // 8 KiB each
    __shared__ u16 Bsl[2][512 * 32];   // 32 KiB each — total 81920 B exactly
    const int t = threadIdx.x;
    const int lane = t & 63, wave = t >> 6;
    const int wm = wave >> 2, wn = wave & 3;
    const int L = lane & 15, g = lane >> 4;
    const size_t row0 = (size_t)blockIdx.x * 128;

    // A reg-staging: thread t owns row t>>2, source slot t&3 (64B-contiguous per 4 lanes)
    const int ar = t >> 2, as = t & 3;
    const float* aptr = Q + (row0 + ar) * FEAT + as * 8;
    const int aw = swz16(ar, as);
    float af[8];

    auto loadA = [&](int ks) {
        const float4* p = (const float4*)(aptr + ks * 32);
        float4 x = p[0], y = p[1];
        af[0] = x.x; af[1] = x.y; af[2] = x.z; af[3] = x.w;
        af[4] = y.x; af[5] = y.y; af[6] = y.z; af[7] = y.w;
    };
    auto writeA = [&](int buf) {
        uint4 w;
        w.x = (u32)f2bf(af[0]) | ((u32)f2bf(af[1]) << 16);
        w.y = (u32)f2bf(af[2]) | ((u32)f2bf(af[3]) << 16);
        w.z = (u32)f2bf(af[4]) | ((u32)f2bf(af[5]) << 16);
        w.w = (u32)f2bf(af[6]) | ((u32)f2bf(af[7]) << 16);
        *(uint4*)&Asl[buf][aw] = w;
    };
    // B staging: LDS dest linear (gl_lds requirement), global source pre-swizzled
    auto stageB = [&](int buf, int ks) {
#pragma unroll
        for (int p = 0; p < 4; ++p) {
            int gi = t + p * 512;            // 2048 granules of 16B: 512 rows x 4 slots
            int r = gi >> 2, cc = gi & 3;
            int s = cc ^ ((r >> 1) & 3);
            gl_lds16(Wt + (size_t)r * FEAT + ks * 32 + s * 8, &Bsl[buf][gi * 8]);
        }
    };

    f32x4 acc[4][8];
#pragma unroll
    for (int mt = 0; mt < 4; ++mt)
#pragma unroll
        for (int nt = 0; nt < 8; ++nt) acc[mt][nt] = f32x4{0.f, 0.f, 0.f, 0.f};

    stageB(0, 0);
    loadA(0);
    writeA(0);
    __syncthreads();

    const int ard = swz16(wm * 64 + L, g);    // + mt*512
    const int brd = swz16(wn * 128 + L, g);   // + nt*512

    int cur = 0;
    for (int ks = 0; ks < 32; ++ks) {
        const int nxt = cur ^ 1;
        if (ks < 31) { stageB(nxt, ks + 1); loadA(ks + 1); }
        bf16x8 a[4], b[8];
#pragma unroll
        for (int mt = 0; mt < 4; ++mt) a[mt] = *(const bf16x8*)&Asl[cur][ard + mt * 512];
#pragma unroll
        for (int nt = 0; nt < 8; ++nt) b[nt] = *(const bf16x8*)&Bsl[cur][brd + nt * 512];
#pragma unroll
        for (int mt = 0; mt < 4; ++mt)
#pragma unroll
            for (int nt = 0; nt < 8; ++nt)
                acc[mt][nt] = __builtin_amdgcn_mfma_f32_16x16x32_bf16(a[mt], b[nt], acc[mt][nt], 0, 0, 0);
        if (ks < 31) writeA(nxt);
        __syncthreads();
        cur = nxt;
    }

    // epilogue: zq bf16 + q2 partial (this wave's 128 cols) -> q2p[wn][row], plain store
    const int c = L;
#pragma unroll
    for (int mt = 0; mt < 4; ++mt) {
#pragma unroll
        for (int j = 0; j < 4; ++j) {
            const int rloc = wm * 64 + mt * 16 + g * 4 + j;
            const size_t r = row0 + rloc;
            float ss = 0.f;
#pragma unroll
            for (int nt = 0; nt < 8; ++nt) {
                float v = acc[mt][nt][j];
                ss += v * v;
                zq[r * EMB + wn * 128 + nt * 16 + c] = f2bf(v);
            }
#pragma unroll
            for (int m = 1; m < 16; m <<= 1) ss += __shfl_xor(ss, m);
            if (c == 0) q2p[(size_t)wn * NQRY + r] = ss;
        }
    }
}

// ---------------- K4: cross GEMM (K=512, N=256 full) + distances + row softmax ----------------
// tile 128M x 256N, wave tile 64x64, swizzled LDS (0 conflicts), 3 blocks/CU.
__global__ __launch_bounds__(512, 4) void k4_scores(const u16* __restrict__ zq,
                                                    const u16* __restrict__ zp,
                                                    const float* __restrict__ q2p,
                                                    const float* __restrict__ p2,
                                                    float* __restrict__ out) {
    __shared__ u16 Asl[2][128 * 32];
    __shared__ u16 Bsl[2][256 * 32];
    __shared__ float p2l[WAYS];
    __shared__ float q2s[128];
    const int t = threadIdx.x;
    const int lane = t & 63, wave = t >> 6;
    const int wm = wave >> 2, wn = wave & 3;
    const size_t row0 = (size_t)blockIdx.x * 128;
    if (t < WAYS) p2l[t] = p2[t];
    if (t >= WAYS && t < WAYS + 128) {
        int r = t - WAYS;
        q2s[r] = (q2p[row0 + r]                    + q2p[(size_t)NQRY + row0 + r]) +
                 (q2p[(size_t)2 * NQRY + row0 + r] + q2p[(size_t)3 * NQRY + row0 + r]);
    }

    auto stage = [&](int buf, int ks) {
        { int r = t >> 2, cc = t & 3;
          int s = cc ^ ((r >> 1) & 3);
          gl_lds16(zq + (row0 + r) * EMB + ks * 32 + s * 8, &Asl[buf][t * 8]); }
#pragma unroll
        for (int p = 0; p < 2; ++p) {
            int gi = t + p * 512;
            int r = gi >> 2, cc = gi & 3;
            int s = cc ^ ((r >> 1) & 3);
            gl_lds16(zp + (size_t)r * EMB + ks * 32 + s * 8, &Bsl[buf][gi * 8]);
        }
    };

    f32x4 acc[4][4];
#pragma unroll
    for (int mt = 0; mt < 4; ++mt)
#pragma unroll
        for (int nt = 0; nt < 4; ++nt) acc[mt][nt] = f32x4{0.f, 0.f, 0.f, 0.f};

    stage(0, 0);
    __syncthreads();

    const int L = lane & 15, g = lane >> 4;
    const int ard = swz16(wm * 64 + L, g);
    const int brd = swz16(wn * 64 + L, g);

    int cur = 0;
    for (int ks = 0; ks < 16; ++ks) {
        const int nxt = cur ^ 1;
        if (ks < 15) stage(nxt, ks + 1);
        bf16x8 a[4], b[4];
#pragma unroll
        for (int mt = 0; mt < 4; ++mt) a[mt] = *(const bf16x8*)&Asl[cur][ard + mt * 512];
#pragma unroll
        for (int nt = 0; nt < 4; ++nt) b[nt] = *(const bf16x8*)&Bsl[cur][brd + nt * 512];
#pragma unroll
        for (int mt = 0; mt < 4; ++mt)
#pragma unroll
            for (int nt = 0; nt < 4; ++nt)
                acc[mt][nt] = __builtin_amdgcn_mfma_f32_16x16x32_bf16(a[mt], b[nt], acc[mt][nt], 0, 0, 0);
        __syncthreads();
        cur = nxt;
    }

    // softmax scratch overlaid on Asl[0] (dead after final barrier)
    float* rmax = (float*)&Asl[0][0];     // [128][4]
    float* rsum = rmax + 512;             // [128][4]
    const int c = L;

    // pass 1: scores + per-wave row max
#pragma unroll
    for (int mt = 0; mt < 4; ++mt)
#pragma unroll
        for (int j = 0; j < 4; ++j) {
            const int rloc = wm * 64 + mt * 16 + g * 4 + j;
            const float qv = q2s[rloc];
            float m_ = -1e30f;
#pragma unroll
            for (int nt = 0; nt < 4; ++nt) {
                float d2 = qv + p2l[wn * 64 + nt * 16 + c] - 2.f * acc[mt][nt][j];
                float s = -sqrtf(fmaxf(d2, 0.f));
                acc[mt][nt][j] = s;
                m_ = fmaxf(m_, s);
            }
#pragma unroll
            for (int m = 1; m < 16; m <<= 1) m_ = fmaxf(m_, __shfl_xor(m_, m));
            if (c == 0) rmax[rloc * 4 + wn] = m_;
        }
    __syncthreads();
    // pass 2: exp + per-wave row sum
#pragma unroll
    for (int mt = 0; mt < 4; ++mt)
#pragma unroll
        for (int j = 0; j < 4; ++j) {
            const int rloc = wm * 64 + mt * 16 + g * 4 + j;
            float m4 = fmaxf(fmaxf(rmax[rloc * 4 + 0], rmax[rloc * 4 + 1]),
                             fmaxf(rmax[rloc * 4 + 2], rmax[rloc * 4 + 3]));
            float s_ = 0.f;
#pragma unroll
            for (int nt = 0; nt < 4; ++nt) {
                float e = __expf(acc[mt][nt][j] - m4);
                acc[mt][nt][j] = e;
                s_ += e;
            }
#pragma unroll
            for (int m = 1; m < 16; m <<= 1) s_ += __shfl_xor(s_, m);
            if (c == 0) rsum[rloc * 4 + wn] = s_;
        }
    __syncthreads();
    // pass 3: normalize + write (fixed-order combine -> deterministic)
#pragma unroll
    for (int mt = 0; mt < 4; ++mt)
#pragma unroll
        for (int j = 0; j < 4; ++j) {
            const int rloc = wm * 64 + mt * 16 + g * 4 + j;
            float inv = 1.f / ((rsum[rloc * 4 + 0] + rsum[rloc * 4 + 1]) +
                               (rsum[rloc * 4 + 2] + rsum[rloc * 4 + 3]));
#pragma unroll
            for (int nt = 0; nt < 4; ++nt)
                out[(row0 + rloc) * WAYS + wn * 64 + nt * 16 + c] = acc[mt][nt][j] * inv;
        }
}

// ---------------- launch ----------------
extern "C" void kernel_launch(void* const* d_in, const int* in_sizes, int n_in,
                              void* d_out, int out_size, void* d_ws, size_t ws_size,
                              hipStream_t stream) {
    (void)in_sizes; (void)n_in; (void)out_size; (void)ws_size;
    const float* simg = (const float*)d_in[0];
    const int*   slab = (const int*)d_in[1];
    const float* qimg = (const float*)d_in[2];
    const float* W    = (const float*)d_in[3];
    // d_in[4] = b : omitted on purpose (cancels in euclidean distance)
    float* out = (float*)d_out;
    char* ws = (char*)d_ws;

    int*   labels = (int*)  (ws + 0);          // 256 KiB
    int*   perm   = (int*)  (ws + 262144);     // 256 KiB
    int*   icounts= (int*)  (ws + 524288);     // 1 KiB
    int*   offs   = (int*)  (ws + 525312);     // 1 KiB
    int*   cursor = (int*)  (ws + 526336);     // 1 KiB
    float* countsF= (float*)(ws + 527360);     // 1 KiB
    float* sums   = (float*)(ws + 528384);     // 1 MiB
    float* p2     = (float*)(ws + 1576960);    // 1 KiB
    u16*   zpb    = (u16*)  (ws + 1577984);    // 256 KiB
    u16*   Wt     = (u16*)  (ws + 1840128);    // 1 MiB
    u16*   zq     = (u16*)  (ws + 2888704);    // 64 MiB
    float* q2p    = (float*)(ws + 69997568);   // 1 MiB (4 per-wave-column partials)

    // NO hipMemsetAsync (150us/node): icounts zeroed in k0; zq/q2p fully overwritten.

    k0_transpose <<<128,        256, 0, stream>>>(W, Wt, icounts);
    k1a_labels   <<<NSUP / 4,   256, 0, stream>>>(slab, labels, icounts);
    k1p_prefix   <<<1,          256, 0, stream>>>(icounts, offs, cursor, countsF);
    k1s_scatter  <<<NSUP / 256, 256, 0, stream>>>(labels, cursor, perm);
    k1c_classsum <<<WAYS * 4,   256, 0, stream>>>(simg, perm, offs, icounts, sums);
    k2_proto     <<<WAYS,       512, 0, stream>>>(sums, countsF, W, zpb, p2);
    k3_zq        <<<NQRY / 128, 512, 0, stream>>>(qimg, Wt, zq, q2p);
    k4_scores    <<<NQRY / 128, 512, 0, stream>>>(zq, zpb, q2p, p2, out);
}

// Round 8
// 363.781 us; speedup vs baseline: 2.6416x; 2.6416x over previous
//
#include <hip/hip_runtime.h>
#include <stdint.h>

#define NSUP 65536
#define NQRY 65536
#define FEAT 1024
#define EMB  512
#define WAYS 256

typedef unsigned short u16;
typedef unsigned int   u32;
typedef __attribute__((ext_vector_type(8))) __bf16 bf16x8;
typedef __attribute__((ext_vector_type(4))) float  f32x4;

// RNE float -> bf16 bits
static __device__ __forceinline__ u16 f2bf(float f) {
    u32 u = __builtin_bit_cast(u32, f);
    u32 r = u + 0x7fffu + ((u >> 16) & 1u);
    return (u16)(r >> 16);
}

// async global -> LDS, 16B per lane (dest must be wave-uniform base + lane*16)
static __device__ __forceinline__ void gl_lds16(const void* g, void* l) {
    __builtin_amdgcn_global_load_lds((const __attribute__((address_space(1))) u32*)g,
                                     (__attribute__((address_space(3))) u32*)l,
                                     16, 0, 0);
}

// swizzled u16-index in a [rows][32 u16] tile: source slot s of row r stored at
// slot s ^ ((r>>1)&3) -> conflict-free b128 reads (verified: SQ_LDS_BANK_CONFLICT=0).
static __device__ __forceinline__ int swz16(int r, int s) {
    return r * 32 + ((s ^ ((r >> 1) & 3)) * 8);
}

// ---------------- K0: W [FEAT][EMB] f32 -> Wt [EMB][FEAT] bf16 (+ zero icounts) ----------------
__global__ __launch_bounds__(256) void k0_transpose(const float* __restrict__ W,
                                                    u16* __restrict__ Wt,
                                                    int* __restrict__ icounts) {
    const int t = threadIdx.x;
    if (blockIdx.x == 0) icounts[t] = 0;   // replaces hipMemsetAsync node (~150us each)
    __shared__ float tile[64][65];
    const int bx = blockIdx.x;
    const int k0 = (bx & 15) * 64;
    const int e0 = (bx >> 4) * 64;
#pragma unroll
    for (int i = 0; i < 16; ++i) {
        int idx = t + i * 256;
        int kk = idx >> 6, ee = idx & 63;
        tile[kk][ee] = W[(size_t)(k0 + kk) * EMB + e0 + ee];
    }
    __syncthreads();
#pragma unroll
    for (int i = 0; i < 16; ++i) {
        int idx = t + i * 256;
        int ee = idx >> 6, kk = idx & 63;
        Wt[(size_t)(e0 + ee) * FEAT + k0 + kk] = f2bf(tile[kk][ee]);
    }
}

// ---------------- K1a: argmax of one-hot rows -> labels, int histogram ----------------
__global__ __launch_bounds__(256) void k1a_labels(const int* __restrict__ sl,
                                                  int* __restrict__ labels,
                                                  int* __restrict__ icounts) {
    const int row = blockIdx.x * 4 + (threadIdx.x >> 6);
    const int lane = threadIdx.x & 63;
    const int4* p = (const int4*)(sl + (size_t)row * WAYS);
    int4 v = p[lane];
    int my = -1;
    if (v.x) my = lane * 4 + 0;
    if (v.y) my = lane * 4 + 1;
    if (v.z) my = lane * 4 + 2;
    if (v.w) my = lane * 4 + 3;
#pragma unroll
    for (int m = 32; m; m >>= 1) my = max(my, __shfl_xor(my, m));
    if (lane == 0) {
        labels[row] = my;
        atomicAdd(&icounts[my], 1);
    }
}

// ---------------- K1p: exclusive prefix sum over 256 class counts ----------------
__global__ __launch_bounds__(256) void k1p_prefix(const int* __restrict__ icounts,
                                                  int* __restrict__ offs,
                                                  int* __restrict__ cursor,
                                                  float* __restrict__ countsF) {
    __shared__ int s[256];
    const int t = threadIdx.x;
    const int v = icounts[t];
    s[t] = v;
    __syncthreads();
    for (int d = 1; d < 256; d <<= 1) {
        int x = (t >= d) ? s[t - d] : 0;
        __syncthreads();
        s[t] += x;
        __syncthreads();
    }
    const int exc = s[t] - v;
    offs[t] = exc;
    cursor[t] = exc;
    countsF[t] = (float)v;
}

// ---------------- K1s: scatter row indices by class -> perm ----------------
__global__ __launch_bounds__(256) void k1s_scatter(const int* __restrict__ labels,
                                                   int* __restrict__ cursor,
                                                   int* __restrict__ perm) {
    const int r = blockIdx.x * 256 + threadIdx.x;
    const int lb = labels[r];
    const int pos = atomicAdd(&cursor[lb], 1);
    perm[pos] = r;
}

// ---------------- K1c: per-class feature sums, gather-streaming, NO atomics ----------------
__global__ __launch_bounds__(256) void k1c_classsum(const float* __restrict__ img,
                                                    const int* __restrict__ perm,
                                                    const int* __restrict__ offs,
                                                    const int* __restrict__ icounts,
                                                    float* __restrict__ sums) {
    const int c  = blockIdx.x >> 2;
    const int fs = blockIdx.x & 3;
    const int t  = threadIdx.x;
    const int base = offs[c];
    const int n    = icounts[c];
    const size_t fcol = (size_t)fs * 256 + t;
    float acc = 0.f;
    int i = 0;
    for (; i + 8 <= n; i += 8) {
        int rr[8];
#pragma unroll
        for (int u = 0; u < 8; ++u) rr[u] = perm[base + i + u];
        float v[8];
#pragma unroll
        for (int u = 0; u < 8; ++u) v[u] = img[(size_t)rr[u] * FEAT + fcol];
#pragma unroll
        for (int u = 0; u < 8; ++u) acc += v[u];
    }
    for (; i < n; ++i) acc += img[(size_t)perm[base + i] * FEAT + fcol];
    sums[(size_t)c * FEAT + fcol] = acc;
}

// ---------------- K2: protos: (sums/count) @ W  -> zp_bf16 [WAYS][EMB], p2 ----------------
// NOTE: bias b deliberately omitted everywhere — it cancels in euclidean distance.
__global__ __launch_bounds__(512) void k2_proto(const float* __restrict__ sums,
                                                const float* __restrict__ counts,
                                                const float* __restrict__ W,
                                                u16* __restrict__ zpb,
                                                float* __restrict__ p2) {
    __shared__ float proto[FEAT];
    __shared__ float red[8];
    const int c = blockIdx.x, t = threadIdx.x;
    const float inv = 1.0f / counts[c];
    proto[t]       = sums[(size_t)c * FEAT + t] * inv;
    proto[t + 512] = sums[(size_t)c * FEAT + t + 512] * inv;
    __syncthreads();
    float a0 = 0.f, a1 = 0.f, a2 = 0.f, a3 = 0.f;
#pragma unroll 8
    for (int k = 0; k < FEAT; k += 4) {
        a0 += proto[k + 0] * W[(size_t)(k + 0) * EMB + t];
        a1 += proto[k + 1] * W[(size_t)(k + 1) * EMB + t];
        a2 += proto[k + 2] * W[(size_t)(k + 2) * EMB + t];
        a3 += proto[k + 3] * W[(size_t)(k + 3) * EMB + t];
    }
    float z = (a0 + a1) + (a2 + a3);
    zpb[(size_t)c * EMB + t] = f2bf(z);
    float sq = z * z;
#pragma unroll
    for (int m = 1; m < 64; m <<= 1) sq += __shfl_xor(sq, m);
    if ((t & 63) == 0) red[t >> 6] = sq;
    __syncthreads();
    if (t == 0) {
        float s = 0.f;
#pragma unroll
        for (int i = 0; i < 8; ++i) s += red[i];
        p2[c] = s;
    }
}

// ---------------- K3: z_query GEMM: Q[65536][1024]f32 x Wt[512][1024]bf16 ----------------
// Full-N tile 128M x 512N (Q fetched ONCE), BK=32, 1024 threads = 16 waves (2m x 8n),
// wave tile 64x64, acc[4][4] -> ~124 unified regs -> 4 waves/SIMD, NO spill.
// 2-phase dbuf, swizzled LDS (0 conflicts), LDS exactly 80 KiB.
__global__ __launch_bounds__(1024, 4) void k3_zq(const float* __restrict__ Q,
                                                 const u16* __restrict__ Wt,
                                                 u16* __restrict__ zq,
                                                 float* __restrict__ q2p) {
    __shared__ u16 Asl[2][128 * 32];   // 8 KiB each
    __shared__ u16 Bsl[2][512 * 32];   // 32 KiB each — total 81920 B
    const int t = threadIdx.x;
    const int lane = t & 63, wave = t >> 6;     // 16 waves
    const int wm = wave >> 3, wn = wave & 7;    // 2m x 8n
    const int L = lane & 15, g = lane >> 4;
    const size_t row0 = (size_t)blockIdx.x * 128;

    // A reg-staging by threads < 512: thread owns row t>>2, slot t&3 (8 f32 -> 8 bf16)
    const int ar = t >> 2, as = t & 3;
    const float* aptr = Q + (row0 + ar) * FEAT + as * 8;
    const int aw = swz16(ar, as);
    float af[8];

    auto loadA = [&](int ks) {
        const float4* p = (const float4*)(aptr + ks * 32);
        float4 x = p[0], y = p[1];
        af[0] = x.x; af[1] = x.y; af[2] = x.z; af[3] = x.w;
        af[4] = y.x; af[5] = y.y; af[6] = y.z; af[7] = y.w;
    };
    auto writeA = [&](int buf) {
        uint4 w;
        w.x = (u32)f2bf(af[0]) | ((u32)f2bf(af[1]) << 16);
        w.y = (u32)f2bf(af[2]) | ((u32)f2bf(af[3]) << 16);
        w.z = (u32)f2bf(af[4]) | ((u32)f2bf(af[5]) << 16);
        w.w = (u32)f2bf(af[6]) | ((u32)f2bf(af[7]) << 16);
        *(uint4*)&Asl[buf][aw] = w;
    };
    // B staging: 2048 granules of 16B over 1024 threads; source pre-swizzled
    auto stageB = [&](int buf, int ks) {
#pragma unroll
        for (int p = 0; p < 2; ++p) {
            int gi = t + p * 1024;
            int r = gi >> 2, cc = gi & 3;
            int s = cc ^ ((r >> 1) & 3);
            gl_lds16(Wt + (size_t)r * FEAT + ks * 32 + s * 8, &Bsl[buf][gi * 8]);
        }
    };

    f32x4 acc[4][4];
#pragma unroll
    for (int mt = 0; mt < 4; ++mt)
#pragma unroll
        for (int nt = 0; nt < 4; ++nt) acc[mt][nt] = f32x4{0.f, 0.f, 0.f, 0.f};

    stageB(0, 0);
    if (t < 512) { loadA(0); writeA(0); }
    __syncthreads();

    const int ard = swz16(wm * 64 + L, g);    // + mt*512
    const int brd = swz16(wn * 64 + L, g);    // + nt*512

    int cur = 0;
    for (int ks = 0; ks < 32; ++ks) {
        const int nxt = cur ^ 1;
        if (ks < 31) {
            stageB(nxt, ks + 1);
            if (t < 512) loadA(ks + 1);
        }
        bf16x8 a[4], b[4];
#pragma unroll
        for (int mt = 0; mt < 4; ++mt) a[mt] = *(const bf16x8*)&Asl[cur][ard + mt * 512];
#pragma unroll
        for (int nt = 0; nt < 4; ++nt) b[nt] = *(const bf16x8*)&Bsl[cur][brd + nt * 512];
#pragma unroll
        for (int mt = 0; mt < 4; ++mt)
#pragma unroll
            for (int nt = 0; nt < 4; ++nt)
                acc[mt][nt] = __builtin_amdgcn_mfma_f32_16x16x32_bf16(a[mt], b[nt], acc[mt][nt], 0, 0, 0);
        if (ks < 31 && t < 512) writeA(nxt);
        __syncthreads();
        cur = nxt;
    }

    // epilogue: zq bf16 + q2 partial (this wave's 64 cols) -> q2p[wn][row], plain store
    const int c = L;
#pragma unroll
    for (int mt = 0; mt < 4; ++mt) {
#pragma unroll
        for (int j = 0; j < 4; ++j) {
            const int rloc = wm * 64 + mt * 16 + g * 4 + j;
            const size_t r = row0 + rloc;
            float ss = 0.f;
#pragma unroll
            for (int nt = 0; nt < 4; ++nt) {
                float v = acc[mt][nt][j];
                ss += v * v;
                zq[r * EMB + wn * 64 + nt * 16 + c] = f2bf(v);
            }
#pragma unroll
            for (int m = 1; m < 16; m <<= 1) ss += __shfl_xor(ss, m);
            if (c == 0) q2p[(size_t)wn * NQRY + r] = ss;
        }
    }
}

// ---------------- K4: cross GEMM (K=512, N=256 full) + distances + row softmax ----------------
// tile 128M x 256N, wave tile 64x64, swizzled LDS (0 conflicts). R4-proven structure.
__global__ __launch_bounds__(512, 4) void k4_scores(const u16* __restrict__ zq,
                                                    const u16* __restrict__ zp,
                                                    const float* __restrict__ q2p,
                                                    const float* __restrict__ p2,
                                                    float* __restrict__ out) {
    __shared__ u16 Asl[2][128 * 32];
    __shared__ u16 Bsl[2][256 * 32];
    __shared__ float p2l[WAYS];
    __shared__ float q2s[128];
    const int t = threadIdx.x;
    const int lane = t & 63, wave = t >> 6;
    const int wm = wave >> 2, wn = wave & 3;
    const size_t row0 = (size_t)blockIdx.x * 128;
    if (t < WAYS) p2l[t] = p2[t];
    if (t >= WAYS && t < WAYS + 128) {
        int r = t - WAYS;
        float s0 = 0.f;
#pragma unroll
        for (int p = 0; p < 8; ++p) s0 += q2p[(size_t)p * NQRY + row0 + r];  // fixed order
        q2s[r] = s0;
    }

    auto stage = [&](int buf, int ks) {
        { int r = t >> 2, cc = t & 3;
          int s = cc ^ ((r >> 1) & 3);
          gl_lds16(zq + (row0 + r) * EMB + ks * 32 + s * 8, &Asl[buf][t * 8]); }
#pragma unroll
        for (int p = 0; p < 2; ++p) {
            int gi = t + p * 512;
            int r = gi >> 2, cc = gi & 3;
            int s = cc ^ ((r >> 1) & 3);
            gl_lds16(zp + (size_t)r * EMB + ks * 32 + s * 8, &Bsl[buf][gi * 8]);
        }
    };

    f32x4 acc[4][4];
#pragma unroll
    for (int mt = 0; mt < 4; ++mt)
#pragma unroll
        for (int nt = 0; nt < 4; ++nt) acc[mt][nt] = f32x4{0.f, 0.f, 0.f, 0.f};

    stage(0, 0);
    __syncthreads();

    const int L = lane & 15, g = lane >> 4;
    const int ard = swz16(wm * 64 + L, g);
    const int brd = swz16(wn * 64 + L, g);

    int cur = 0;
    for (int ks = 0; ks < 16; ++ks) {
        const int nxt = cur ^ 1;
        if (ks < 15) stage(nxt, ks + 1);
        bf16x8 a[4], b[4];
#pragma unroll
        for (int mt = 0; mt < 4; ++mt) a[mt] = *(const bf16x8*)&Asl[cur][ard + mt * 512];
#pragma unroll
        for (int nt = 0; nt < 4; ++nt) b[nt] = *(const bf16x8*)&Bsl[cur][brd + nt * 512];
#pragma unroll
        for (int mt = 0; mt < 4; ++mt)
#pragma unroll
            for (int nt = 0; nt < 4; ++nt)
                acc[mt][nt] = __builtin_amdgcn_mfma_f32_16x16x32_bf16(a[mt], b[nt], acc[mt][nt], 0, 0, 0);
        __syncthreads();
        cur = nxt;
    }

    // softmax scratch overlaid on Asl[0] (dead after final barrier)
    float* rmax = (float*)&Asl[0][0];     // [128][4]
    float* rsum = rmax + 512;             // [128][4]
    const int c = L;

    // pass 1: scores + per-wave row max
#pragma unroll
    for (int mt = 0; mt < 4; ++mt)
#pragma unroll
        for (int j = 0; j < 4; ++j) {
            const int rloc = wm * 64 + mt * 16 + g * 4 + j;
            const float qv = q2s[rloc];
            float m_ = -1e30f;
#pragma unroll
            for (int nt = 0; nt < 4; ++nt) {
                float d2 = qv + p2l[wn * 64 + nt * 16 + c] - 2.f * acc[mt][nt][j];
                float s = -sqrtf(fmaxf(d2, 0.f));
                acc[mt][nt][j] = s;
                m_ = fmaxf(m_, s);
            }
#pragma unroll
            for (int m = 1; m < 16; m <<= 1) m_ = fmaxf(m_, __shfl_xor(m_, m));
            if (c == 0) rmax[rloc * 4 + wn] = m_;
        }
    __syncthreads();
    // pass 2: exp + per-wave row sum
#pragma unroll
    for (int mt = 0; mt < 4; ++mt)
#pragma unroll
        for (int j = 0; j < 4; ++j) {
            const int rloc = wm * 64 + mt * 16 + g * 4 + j;
            float m4 = fmaxf(fmaxf(rmax[rloc * 4 + 0], rmax[rloc * 4 + 1]),
                             fmaxf(rmax[rloc * 4 + 2], rmax[rloc * 4 + 3]));
            float s_ = 0.f;
#pragma unroll
            for (int nt = 0; nt < 4; ++nt) {
                float e = __expf(acc[mt][nt][j] - m4);
                acc[mt][nt][j] = e;
                s_ += e;
            }
#pragma unroll
            for (int m = 1; m < 16; m <<= 1) s_ += __shfl_xor(s_, m);
            if (c == 0) rsum[rloc * 4 + wn] = s_;
        }
    __syncthreads();
    // pass 3: normalize + write (fixed-order combine -> deterministic)
#pragma unroll
    for (int mt = 0; mt < 4; ++mt)
#pragma unroll
        for (int j = 0; j < 4; ++j) {
            const int rloc = wm * 64 + mt * 16 + g * 4 + j;
            float inv = 1.f / ((rsum[rloc * 4 + 0] + rsum[rloc * 4 + 1]) +
                               (rsum[rloc * 4 + 2] + rsum[rloc * 4 + 3]));
#pragma unroll
            for (int nt = 0; nt < 4; ++nt)
                out[(row0 + rloc) * WAYS + wn * 64 + nt * 16 + c] = acc[mt][nt][j] * inv;
        }
}

// ---------------- launch ----------------
extern "C" void kernel_launch(void* const* d_in, const int* in_sizes, int n_in,
                              void* d_out, int out_size, void* d_ws, size_t ws_size,
                              hipStream_t stream) {
    (void)in_sizes; (void)n_in; (void)out_size; (void)ws_size;
    const float* simg = (const float*)d_in[0];
    const int*   slab = (const int*)d_in[1];
    const float* qimg = (const float*)d_in[2];
    const float* W    = (const float*)d_in[3];
    // d_in[4] = b : omitted on purpose (cancels in euclidean distance)
    float* out = (float*)d_out;
    char* ws = (char*)d_ws;

    int*   labels = (int*)  (ws + 0);          // 256 KiB
    int*   perm   = (int*)  (ws + 262144);     // 256 KiB
    int*   icounts= (int*)  (ws + 524288);     // 1 KiB
    int*   offs   = (int*)  (ws + 525312);     // 1 KiB
    int*   cursor = (int*)  (ws + 526336);     // 1 KiB
    float* countsF= (float*)(ws + 527360);     // 1 KiB
    float* sums   = (float*)(ws + 528384);     // 1 MiB
    float* p2     = (float*)(ws + 1576960);    // 1 KiB
    u16*   zpb    = (u16*)  (ws + 1577984);    // 256 KiB
    u16*   Wt     = (u16*)  (ws + 1840128);    // 1 MiB
    u16*   zq     = (u16*)  (ws + 2888704);    // 64 MiB
    float* q2p    = (float*)(ws + 69997568);   // 2 MiB (8 per-wave-column partials)

    // NO hipMemsetAsync (150us/node): icounts zeroed in k0; zq/q2p fully overwritten.

    k0_transpose <<<128,        256, 0, stream>>>(W, Wt, icounts);
    k1a_labels   <<<NSUP / 4,   256, 0, stream>>>(slab, labels, icounts);
    k1p_prefix   <<<1,          256, 0, stream>>>(icounts, offs, cursor, countsF);
    k1s_scatter  <<<NSUP / 256, 256, 0, stream>>>(labels, cursor, perm);
    k1c_classsum <<<WAYS * 4,   256, 0, stream>>>(simg, perm, offs, icounts, sums);
    k2_proto     <<<WAYS,       512, 0, stream>>>(sums, countsF, W, zpb, p2);
    k3_zq        <<<NQRY / 128, 1024, 0, stream>>>(qimg, Wt, zq, q2p);
    k4_scores    <<<NQRY / 128, 512, 0, stream>>>(zq, zpb, q2p, p2, out);
}